// Round 2
// baseline (476.051 us; speedup 1.0000x reference)
//
#include <hip/hip_runtime.h>
#include <cstdint>
#include <cstddef>

// ---------- types ----------
typedef __bf16 bf16x8 __attribute__((ext_vector_type(8)));
typedef float f32x4 __attribute__((ext_vector_type(4)));

__device__ static inline unsigned short f32_to_bf16_rne(float f) {
  unsigned int u = __float_as_uint(f);
  unsigned int r = 0x7FFFu + ((u >> 16) & 1u);
  return (unsigned short)((u + r) >> 16);
}

__device__ static inline void async16(const void* g, void* l) {
  __builtin_amdgcn_global_load_lds(
      (const __attribute__((address_space(1))) void*)g,
      (__attribute__((address_space(3))) void*)l,
      16, 0, 0);
}

// ---------- prep: Ucol[i] = U[i][1024] (contiguous fp32) ----------
__global__ __launch_bounds__(256) void prep_Ucol(const float* __restrict__ U,
                                                 float* __restrict__ Ucol) {
  const int i = blockIdx.x * 256 + threadIdx.x;
  Ucol[i] = U[(size_t)i * 1025 + 1024];
}

// ---------- prep: U_t[j][i] = bf16(U[i][j]), LDS-tiled transpose ----------
__global__ __launch_bounds__(256) void prep_U(const float* __restrict__ U,
                                              unsigned short* __restrict__ Ut) {
  __shared__ float tile[32][33];
  const int i0 = blockIdx.y * 32, j0 = blockIdx.x * 32;
  const int tx = threadIdx.x & 31, ty = threadIdx.x >> 5;  // 32 x 8
#pragma unroll
  for (int r = 0; r < 32; r += 8)
    tile[ty + r][tx] = U[(size_t)(i0 + ty + r) * 1025 + j0 + tx];
  __syncthreads();
#pragma unroll
  for (int r = 0; r < 32; r += 8)
    Ut[(size_t)(j0 + ty + r) * 1024 + i0 + tx] =
        f32_to_bf16_rne(tile[tx][ty + r]);
}

// ---------- prep: cast D,H rows to bf16; c[r], t[r] biases ----------
// Block = 16 rows. thread t -> row (t>>4), column phase (t&15).
// Lane chunk q reads float4 at col = seg*4 + q*64: each 16-lane row-group's
// access is contiguous 256B per instruction (4 lanes per 64B line, fully
// consumed). Reduce = 4 shfl levels per 16-lane group (amortized: 8 shfls
// per 4 rows per wave). No LDS, no barrier.
__global__ __launch_bounds__(256, 8) void prep_rows(
    const float* __restrict__ D, const float* __restrict__ H,
    const float* __restrict__ Ucol, const float* __restrict__ W,
    unsigned short* __restrict__ Db, unsigned short* __restrict__ Hb,
    float* __restrict__ cvec, float* __restrict__ tvec) {
  const int tid = threadIdx.x;
  const int rloc = tid >> 4;  // block-local row 0..15
  const int seg = tid & 15;   // column phase 0..15
  const int grow = blockIdx.x * 16 + rloc;
  const size_t base = (size_t)grow * 1024;

  float cp = 0.0f, tp = 0.0f;
#pragma unroll
  for (int g = 0; g < 4; ++g) {
    float4 d4[4], h4[4];
#pragma unroll
    for (int q = 0; q < 4; ++q) {
      const int col = seg * 4 + (g * 4 + q) * 64;
      d4[q] = *(const float4*)(D + base + col);
      h4[q] = *(const float4*)(H + base + col);
    }
#pragma unroll
    for (int q = 0; q < 4; ++q) {
      const int col = seg * 4 + (g * 4 + q) * 64;
      const float4 uc = *(const float4*)(Ucol + col);
      const float4 wh = *(const float4*)(W + col);
      const float4 wd = *(const float4*)(W + 1025 + col);

      ushort4 db, hb;
      db.x = f32_to_bf16_rne(d4[q].x); db.y = f32_to_bf16_rne(d4[q].y);
      db.z = f32_to_bf16_rne(d4[q].z); db.w = f32_to_bf16_rne(d4[q].w);
      hb.x = f32_to_bf16_rne(h4[q].x); hb.y = f32_to_bf16_rne(h4[q].y);
      hb.z = f32_to_bf16_rne(h4[q].z); hb.w = f32_to_bf16_rne(h4[q].w);
      *(ushort4*)(Db + base + col) = db;
      *(ushort4*)(Hb + base + col) = hb;

      cp += d4[q].x * uc.x + d4[q].y * uc.y + d4[q].z * uc.z +
            d4[q].w * uc.w;
      cp += h4[q].x * wh.x + h4[q].y * wh.y + h4[q].z * wh.z +
            h4[q].w * wh.w;
      tp += d4[q].x * wd.x + d4[q].y * wd.y + d4[q].z * wd.z +
            d4[q].w * wd.w;
    }
  }

  // reduce across the 16 lanes of this row-group
  cp += __shfl_down(cp, 8);
  tp += __shfl_down(tp, 8);
  cp += __shfl_down(cp, 4);
  tp += __shfl_down(tp, 4);
  cp += __shfl_down(cp, 2);
  tp += __shfl_down(tp, 2);
  cp += __shfl_down(cp, 1);
  tp += __shfl_down(tp, 1);
  if (seg == 0) {
    cvec[grow] = cp + W[1024];
    tvec[grow] = tp;
  }
}

// ---------- MFMA GEMM: C[m][n] = sum_k A[m][k] * Bt[n][k] ----------
// XOR-swizzled LDS: slot chunk ch of row holds global chunk ch^(row&7).
// Staging permutes per-lane global sources (LDS dest stays lane-contiguous,
// satisfying global_load_lds's wave-uniform-base + lane*16 constraint).
// XSWZ: bijective XCD-aware block swizzle (requires nwg % 8 == 0); groups the
// 8 n-blocks sharing an A m-panel onto one XCD's L2.
template <bool FUSED, bool XSWZ>
__global__ __launch_bounds__(256) void gemm_bt(
    const unsigned short* __restrict__ A, const unsigned short* __restrict__ Bt,
    void* __restrict__ Cv, const float* __restrict__ rowBias,
    const float* __restrict__ colBias, int M, int N, int K,
    long sA, long sB, long sC) {
  __shared__ unsigned short As[128 * 64];
  __shared__ unsigned short Bs[128 * 64];

  const int tid = threadIdx.x;
  const int lane = tid & 63;
  const int wave = tid >> 6;
  const int wm = wave >> 1, wn = wave & 1;
  const int bz = blockIdx.z;

  int bx = blockIdx.x, by = blockIdx.y;
  if constexpr (XSWZ) {
    const int nwg = gridDim.x * gridDim.y;
    const int b = by * gridDim.x + bx;
    const int s = (b & 7) * (nwg >> 3) + (b >> 3);
    bx = s % gridDim.x;
    by = s / gridDim.x;
  }
  const int m0 = by * 128;
  const int n0 = bx * 128;

  const unsigned short* Ab = A + (size_t)bz * (size_t)sA;
  const unsigned short* Bb = Bt + (size_t)bz * (size_t)sB;

  size_t aOff[4], bOff[4];
  int ldsOff[4];
#pragma unroll
  for (int q = 0; q < 4; ++q) {
    int e = (q * 256 + tid) * 8;   // bf16 element index in 128x64 tile
    int row = e >> 6;              // tile-local row 0..127
    int ch = (e >> 3) & 7;         // chunk-of-8 within row
    int chSw = ch ^ (row & 7);     // swizzled source chunk
    ldsOff[q] = e;
    aOff[q] = (size_t)(m0 + row) * K + chSw * 8;
    bOff[q] = (size_t)(n0 + row) * K + chSw * 8;
  }

  const f32x4 zero = {0.0f, 0.0f, 0.0f, 0.0f};
  f32x4 acc[4][4];
#pragma unroll
  for (int i = 0; i < 4; ++i)
#pragma unroll
    for (int j = 0; j < 4; ++j) acc[i][j] = zero;

  const int rr = lane & 15;
  const int qd = lane >> 4;
  const int c0 = qd ^ (rr & 7);            // swizzled base chunk
  const int aRow = (wm * 64 + rr) * 64;
  const int bRow = (wn * 64 + rr) * 64;

  for (int k0 = 0; k0 < K; k0 += 64) {
#pragma unroll
    for (int q = 0; q < 4; ++q) async16(Ab + aOff[q] + k0, &As[ldsOff[q]]);
#pragma unroll
    for (int q = 0; q < 4; ++q) async16(Bb + bOff[q] + k0, &Bs[ldsOff[q]]);
    __syncthreads();

#pragma unroll
    for (int kk = 0; kk < 64; kk += 32) {
      const int co = (c0 ^ (kk >> 3)) * 8;  // kk=0 -> c0, kk=32 -> c0^4
      bf16x8 af[4], bfr[4];
#pragma unroll
      for (int mt = 0; mt < 4; ++mt)
        af[mt] = *(const bf16x8*)&As[aRow + mt * 16 * 64 + co];
#pragma unroll
      for (int nt = 0; nt < 4; ++nt)
        bfr[nt] = *(const bf16x8*)&Bs[bRow + nt * 16 * 64 + co];
#pragma unroll
      for (int mt = 0; mt < 4; ++mt)
#pragma unroll
        for (int nt = 0; nt < 4; ++nt)
          acc[mt][nt] = __builtin_amdgcn_mfma_f32_16x16x32_bf16(
              af[mt], bfr[nt], acc[mt][nt], 0, 0, 0);
    }
    __syncthreads();
  }

  // epilogue: C/D layout col=lane&15, row=(lane>>4)*4+reg
  const int cl = lane & 15;
  const int rq = (lane >> 4) * 4;
  if constexpr (FUSED) {
    float* Cf = (float*)Cv + (size_t)bz * (size_t)sC;
#pragma unroll
    for (int mt = 0; mt < 4; ++mt) {
      const int rbase = wm * 64 + mt * 16 + rq;
#pragma unroll
      for (int nt = 0; nt < 4; ++nt) {
        const int c = n0 + wn * 64 + nt * 16 + cl;
        const float cb = colBias[(size_t)bz * N + c];
#pragma unroll
        for (int r = 0; r < 4; ++r) {
          const int gr = m0 + rbase + r;
          Cf[(size_t)gr * N + c] =
              acc[mt][nt][r] + rowBias[(size_t)bz * M + gr] + cb;
        }
      }
    }
  } else {
    unsigned short* Cu = (unsigned short*)Cv;
#pragma unroll
    for (int mt = 0; mt < 4; ++mt) {
      const int rbase = wm * 64 + mt * 16 + rq;
#pragma unroll
      for (int nt = 0; nt < 4; ++nt) {
        const int c = n0 + wn * 64 + nt * 16 + cl;
#pragma unroll
        for (int r = 0; r < 4; ++r) {
          const int gr = m0 + rbase + r;
          Cu[(size_t)gr * N + c] = f32_to_bf16_rne(acc[mt][nt][r]);
        }
      }
    }
  }
}

// ---------- launch ----------
extern "C" void kernel_launch(void* const* d_in, const int* in_sizes, int n_in,
                              void* d_out, int out_size, void* d_ws,
                              size_t ws_size, hipStream_t stream) {
  const float* D = (const float*)d_in[0];  // (64,512,1024)
  const float* H = (const float*)d_in[1];  // (64,512,1024)
  const float* U = (const float*)d_in[2];  // (1024,1025)
  const float* W = (const float*)d_in[3];  // (2049,)
  float* out = (float*)d_out;              // (64,512,512)

  char* ws = (char*)d_ws;
  const size_t SZ = (size_t)32768 * 1024 * 2;  // 64 MiB per bf16 matrix
  unsigned short* Db = (unsigned short*)(ws);
  unsigned short* Hb = (unsigned short*)(ws + SZ);
  unsigned short* DU = (unsigned short*)(ws + 2 * SZ);
  unsigned short* Ut = (unsigned short*)(ws + 3 * SZ);
  float* cvec = (float*)(ws + 3 * SZ + (size_t)1024 * 1024 * 2);
  float* tvec = cvec + 32768;
  float* Ucol = tvec + 32768;

  prep_Ucol<<<dim3(4), dim3(256), 0, stream>>>(U, Ucol);
  prep_U<<<dim3(32, 32), dim3(256), 0, stream>>>(U, Ut);
  prep_rows<<<dim3(2048), dim3(256), 0, stream>>>(D, H, Ucol, W, Db, Hb, cvec,
                                                  tvec);

  // GEMM1: DU[r][j] = sum_i D[r][i] * U[i][j]   (M=32768, N=1024, K=1024)
  gemm_bt<false, true><<<dim3(8, 256, 1), dim3(256), 0, stream>>>(
      Db, Ut, (void*)DU, nullptr, nullptr, 32768, 1024, 1024, 0, 0, 0);

  // GEMM2: out[b][x][y] = sum_j DU[b,x,j]*H[b,y,j] + c[b,x] + t[b,y]
  gemm_bt<true, false><<<dim3(4, 4, 64), dim3(256), 0, stream>>>(
      DU, Hb, (void*)out, cvec, tvec, 512, 512, 1024,
      (long)512 * 1024, (long)512 * 1024, (long)512 * 512);
}